// Round 1
// baseline (290.700 us; speedup 1.0000x reference)
//
#include <hip/hip_runtime.h>
#include <hip/hip_bf16.h>

// Problem constants
#define BB 8
#define NN 8192
#define CC 64
#define PP 2048
#define KK 16
#define H1 64
#define H2 128
// C_IN = 2*64+6 = 134; layer-1 K padded to 160 (cols: 0..66 diff, 67..71 zero,
// 72..138 tiled, 139..159 zero). layer-2 K = 64, rows padded to 72 bf16 vs banks.
#define K1PAD 160
#define K2PAD 72

typedef float  f32x4 __attribute__((ext_vector_type(4)));
typedef short  s16x8 __attribute__((ext_vector_type(8)));

// ---- workspace layout (bytes) ----
#define OFF_FXT   0u                    // B*N*68 f32 = 17,825,792
#define OFF_PTS4  17825792u             // B*N float4 = 2,097,152
#define OFF_KNN   19922944u             // B*P*16 int  = 1,048,576
#define OFF_W1P   20971520u             // 64*160 bf16 = 20,480
#define OFF_W2P   20992000u             // 128*72 bf16 = 18,432
#define OFF_C1    21010432u             // 64 f32
#define OFF_C2    21010688u             // 128 f32

static __device__ __forceinline__ unsigned short bf16b(float v) {
    __hip_bfloat16 h = __float2bfloat16(v);
    return *reinterpret_cast<unsigned short*>(&h);
}
static __device__ __forceinline__ unsigned pk2(float a, float b) {
    return ((unsigned)bf16b(b) << 16) | (unsigned)bf16b(a);
}

// ---------------- K0: fold BN into weights, write bf16 W1p/W2p + c1/c2 ----
__global__ void k0_weights(const float* __restrict__ W1, const float* __restrict__ b1,
                           const float* __restrict__ g1, const float* __restrict__ be1,
                           const float* __restrict__ m1, const float* __restrict__ v1,
                           const float* __restrict__ W2, const float* __restrict__ b2,
                           const float* __restrict__ g2, const float* __restrict__ be2,
                           const float* __restrict__ m2, const float* __restrict__ v2,
                           unsigned short* __restrict__ w1p, unsigned short* __restrict__ w2p,
                           float* __restrict__ c1, float* __restrict__ c2) {
    int i = blockIdx.x * 256 + threadIdx.x;
    if (i < 64 * K1PAD) {
        int n = i / K1PAD, c = i - n * K1PAD;
        float s = g1[n] * rsqrtf(v1[n] + 1e-5f);
        float val = 0.f;
        if (c < 67)                 val = W1[n * 134 + c] * s;        // diff half
        else if (c >= 72 && c < 139) val = W1[n * 134 + (c - 5)] * s; // tiled half
        w1p[i] = bf16b(val);
    }
    int j = i - 64 * K1PAD;
    if (j >= 0 && j < 128 * K2PAD) {
        int o = j / K2PAD, k = j - o * K2PAD;
        float s = g2[o] * rsqrtf(v2[o] + 1e-5f);
        w2p[j] = bf16b((k < 64) ? W2[o * 64 + k] * s : 0.f);
    }
    int l = i - (64 * K1PAD + 128 * K2PAD);
    if (l >= 0 && l < 64) {
        float s = g1[l] * rsqrtf(v1[l] + 1e-5f);
        c1[l] = s * (b1[l] - m1[l]) + be1[l];
    }
    int p = l - 64;
    if (p >= 0 && p < 128) {
        float s = g2[p] * rsqrtf(v2[p] + 1e-5f);
        c2[p] = s * (b2[p] - m2[p]) + be2[p];
    }
}

// ---------------- K1: transpose feat -> fxt[b][n][68], pts4, out0, out2 ----
__global__ __launch_bounds__(512) void k1_prep(const float* __restrict__ xyz,
                                               const float* __restrict__ feat,
                                               float* __restrict__ fxt,
                                               float4* __restrict__ pts4,
                                               float* __restrict__ out0,
                                               float* __restrict__ out2) {
    __shared__ float tile[68][65];
    int b  = blockIdx.x >> 7;          // 128 n-blocks per batch
    int n0 = (blockIdx.x & 127) * 64;
    int tx = threadIdx.x & 63, ty = threadIdx.x >> 6;   // 64 x 8
    for (int c = ty; c < 68; c += 8) {
        float v;
        if (c < 64)       v = feat[((size_t)b * 64 + c) * NN + n0 + tx];
        else if (c < 67)  v = xyz[((size_t)b * NN + n0 + tx) * 3 + (c - 64)];
        else              v = 0.f;
        tile[c][tx] = v;
    }
    __syncthreads();
    // coalesced fxt write
    size_t base = ((size_t)b * NN + n0) * 68;
    for (int e = threadIdx.x; e < 64 * 68; e += 512) {
        int nl = e / 68, c = e - nl * 68;
        fxt[base + e] = tile[c][nl];
    }
    if (threadIdx.x < 64) {
        int n = n0 + threadIdx.x;
        float x = tile[64][threadIdx.x], y = tile[65][threadIdx.x], z = tile[66][threadIdx.x];
        pts4[(size_t)b * NN + n] = make_float4(x, y, z, x * x + y * y + z * z);
        if (n0 < PP) out2[b * PP + n] = (float)n;   // sample_idx as float
    }
    if (n0 < PP) {
        for (int e = threadIdx.x; e < 64 * 3; e += 512) {
            int nl = e / 3, d = e - nl * 3;
            out0[((size_t)b * PP + n0 + nl) * 3 + d] = tile[64 + d][nl];
        }
    }
}

// ---------------- K2: exact KNN (wave handles 16 queries) ----
__global__ void k2_knn(const float4* __restrict__ pts4, int* __restrict__ knn) {
    __shared__ float sh_bd[4][512];
    __shared__ int   sh_bi[4][512];
    __shared__ float sh_T[4][16];
    __shared__ unsigned long long sh_mask[4][16];
    __shared__ int   sh_cnt[4];

    int lane = threadIdx.x & 63;
    int wv   = threadIdx.x >> 6;
    int wg   = blockIdx.x * 4 + wv;          // 1024 waves total
    int b    = wg >> 7;                      // 128 waves per batch
    int qb   = (wg & 127) * 16;              // 16 queries per wave
    size_t pb = (size_t)b * NN;

    if (lane == 0) sh_cnt[wv] = 0;

    // query coefficients: lane l<16 holds query qb+l
    float4 qc = make_float4(0.f, 0.f, 0.f, 0.f);
    if (lane < 16) qc = pts4[pb + qb + lane];
    float qx2 = -2.f * qc.x, qy2 = -2.f * qc.y, qz2 = -2.f * qc.z;

    // broadcast to per-q register arrays
    float bx[16], by[16], bz[16];
#pragma unroll
    for (int q = 0; q < 16; ++q) {
        bx[q] = __shfl(qx2, q); by[q] = __shfl(qy2, q); bz[q] = __shfl(qz2, q);
    }

    // Phase 1: per-lane running min over its contiguous 128-candidate block
    float m[16];
#pragma unroll
    for (int q = 0; q < 16; ++q) m[q] = 3.402823466e+38f;
    for (int t = 0; t < 16; ++t) {
        float4 cc[8];
#pragma unroll
        for (int i = 0; i < 8; ++i) cc[i] = pts4[pb + lane * 128 + t * 8 + i];
#pragma unroll
        for (int q = 0; q < 16; ++q) {
            float x = bx[q], y = by[q], z = bz[q];
#pragma unroll
            for (int i = 0; i < 8; ++i) {
                float e = fmaf(z, cc[i].z, fmaf(y, cc[i].y, fmaf(x, cc[i].x, cc[i].w)));
                m[q] = fminf(m[q], e);
            }
        }
    }

    // Phase T: T_q = 16th smallest lane-min (bitonic sort of copies across lanes)
#pragma unroll
    for (int q = 0; q < 16; ++q) {
        float v = m[q];
#pragma unroll
        for (int k = 2; k <= 64; k <<= 1) {
#pragma unroll
            for (int j = k >> 1; j > 0; j >>= 1) {
                float p = __shfl_xor(v, j, 64);
                bool up = ((lane & k) == 0);
                bool lo = ((lane & j) == 0);
                float mn = fminf(v, p), mx = fmaxf(v, p);
                v = (up == lo) ? mn : mx;
            }
        }
        float T = __shfl(v, 15, 64);
        unsigned long long mask = __ballot(m[q] <= T);
        if (lane == 0) { sh_T[wv][q] = T; sh_mask[wv][q] = mask; }
    }
    __syncthreads();

    // Phases 2+3 per query
    for (int q = 0; q < 16; ++q) {
        float tq = sh_T[wv][q];
        unsigned long long mask = sh_mask[wv][q];
        float x = bx[q], y = by[q], z = bz[q];
        while (mask) {
            int sl = __ffsll(mask) - 1; mask &= mask - 1;
#pragma unroll
            for (int st = 0; st < 2; ++st) {
                int n = sl * 128 + st * 64 + lane;
                float4 c = pts4[pb + n];
                float e = fmaf(z, c.z, fmaf(y, c.y, fmaf(x, c.x, c.w)));
                if (e <= tq) {
                    int pos = atomicAdd(&sh_cnt[wv], 1);
                    if (pos < 512) { sh_bd[wv][pos] = e; sh_bi[wv][pos] = n; }
                }
            }
        }
        __syncthreads();
        int M = min(sh_cnt[wv], 512);
        for (int i = lane; i < M; i += 64) {
            float di = sh_bd[wv][i]; int ni = sh_bi[wv][i];
            int rank = 0;
            for (int j = 0; j < M; ++j) {
                float dj = sh_bd[wv][j]; int nj = sh_bi[wv][j];
                rank += (dj < di || (dj == di && nj < ni)) ? 1 : 0;
            }
            if (rank < 16) knn[((size_t)b * PP + qb + q) * KK + rank] = ni;
        }
        __syncthreads();
        if (lane == 0) sh_cnt[wv] = 0;
        __syncthreads();
    }
}

// ---------------- K3: gather + MFMA MLP + maxpool ----
__global__ __launch_bounds__(256, 2) void k3_mlp(const float* __restrict__ fxt,
                                                 const int* __restrict__ knn,
                                                 const unsigned short* __restrict__ w1p,
                                                 const unsigned short* __restrict__ w2p,
                                                 const float* __restrict__ c1,
                                                 const float* __restrict__ c2,
                                                 float* __restrict__ out1) {
    // per-wave LDS segment: [0,5120) E(16x160 bf16), [5120,7424) h1(16x72 bf16),
    // [7424,7696) t4 (17 float4), [7696,7832) tbd (34 u32)
    __shared__ __align__(16) char smem[4 * 8192];
    int lane = threadIdx.x & 63;
    int wv   = threadIdx.x >> 6;
    int wg   = blockIdx.x * 4 + wv;            // 2048 waves
    char* seg = smem + wv * 8192;
    float4* sh_t4 = (float4*)(seg + 7424);
    unsigned* sh_tbd = (unsigned*)(seg + 7696);
    unsigned short* h1l = (unsigned short*)(seg + 5120);

    int col = lane & 15, quad = lane >> 4;

    // preload W fragments (B-operand: B[k][n] = Wp[n][k]) + biases
    s16x8 w1f[5][4];
#pragma unroll
    for (int ks = 0; ks < 5; ++ks)
#pragma unroll
        for (int nt = 0; nt < 4; ++nt)
            w1f[ks][nt] = *(const s16x8*)(w1p + (nt * 16 + col) * K1PAD + ks * 32 + quad * 8);
    s16x8 w2f[2][8];
#pragma unroll
    for (int ks = 0; ks < 2; ++ks)
#pragma unroll
        for (int nt = 0; nt < 8; ++nt)
            w2f[ks][nt] = *(const s16x8*)(w2p + (nt * 16 + col) * K2PAD + ks * 32 + quad * 8);
    float c1v[4], c2v[8];
#pragma unroll
    for (int nt = 0; nt < 4; ++nt) c1v[nt] = c1[nt * 16 + col];
#pragma unroll
    for (int nt = 0; nt < 8; ++nt) c2v[nt] = c2[nt * 16 + col];

    for (int it = 0; it < 8; ++it) {
        int qlin = wg + 2048 * it;
        int b = qlin >> 11, qq = qlin & 2047;
        const float4* fx4 = (const float4*)fxt;
        __syncthreads();
        // stage tiled row (query's own features)
        if (lane < 17) {
            float4 v = fx4[((size_t)b * NN + qq) * 17 + lane];
            sh_t4[lane] = v;
            sh_tbd[lane * 2]     = pk2(v.x, v.y);
            sh_tbd[lane * 2 + 1] = pk2(v.z, v.w);
        }
        __syncthreads();
        // build E rows: r = lane>>2 (edge), s = lane&3 (sublane)
        {
            int r = lane >> 2, s = lane & 3;
            int nidx = knn[((size_t)b * PP + qq) * KK + r];
            const float4* rowp = fx4 + ((size_t)b * NN + nidx) * 17;
            char* erow = seg + r * 320;
#pragma unroll
            for (int j = 0; j < 5; ++j) {
                int c4 = j * 4 + s;
                if (c4 < 17) {
                    float4 v = rowp[c4], t = sh_t4[c4];
                    *(unsigned*)(erow + c4 * 8)     = pk2(v.x - t.x, v.y - t.y);
                    *(unsigned*)(erow + c4 * 8 + 4) = pk2(v.z - t.z, v.w - t.w);
                }
            }
            for (int j = s; j < 34; j += 4)
                *(unsigned*)(erow + 144 + j * 4) = sh_tbd[j];
#pragma unroll
            for (int j = s; j < 12; j += 4) {
                int w = (j < 2) ? (34 + j) : (68 + j);
                *(unsigned*)(erow + w * 4) = 0u;
            }
        }
        __syncthreads();
        // GEMM1: h1 = relu(E * W1p^T + c1)
        f32x4 acc1[4];
#pragma unroll
        for (int nt = 0; nt < 4; ++nt) acc1[nt] = (f32x4){0.f, 0.f, 0.f, 0.f};
#pragma unroll
        for (int ks = 0; ks < 5; ++ks) {
            s16x8 a = *(const s16x8*)(seg + (lane & 15) * 320 + ks * 64 + quad * 16);
#pragma unroll
            for (int nt = 0; nt < 4; ++nt)
                acc1[nt] = __builtin_amdgcn_mfma_f32_16x16x32_bf16(a, w1f[ks][nt], acc1[nt], 0, 0, 0);
        }
#pragma unroll
        for (int nt = 0; nt < 4; ++nt) {
#pragma unroll
            for (int r = 0; r < 4; ++r) {
                float y = fmaxf(acc1[nt][r] + c1v[nt], 0.f);
                h1l[(quad * 4 + r) * K2PAD + nt * 16 + col] = bf16b(y);
            }
        }
        __syncthreads();
        // GEMM2: h2 = relu(h1 * W2p^T + c2); maxpool rows
        f32x4 acc2[8];
#pragma unroll
        for (int nt = 0; nt < 8; ++nt) acc2[nt] = (f32x4){0.f, 0.f, 0.f, 0.f};
#pragma unroll
        for (int ks = 0; ks < 2; ++ks) {
            s16x8 a = *(const s16x8*)(seg + 5120 + (lane & 15) * 144 + ks * 64 + quad * 16);
#pragma unroll
            for (int nt = 0; nt < 8; ++nt)
                acc2[nt] = __builtin_amdgcn_mfma_f32_16x16x32_bf16(a, w2f[ks][nt], acc2[nt], 0, 0, 0);
        }
#pragma unroll
        for (int nt = 0; nt < 8; ++nt) {
            float m0 = fmaxf(fmaxf(acc2[nt][0], acc2[nt][1]), fmaxf(acc2[nt][2], acc2[nt][3]));
            m0 = m0 + c2v[nt];
            m0 = fmaxf(m0, 0.f);
            m0 = fmaxf(m0, __shfl_xor(m0, 16, 64));
            m0 = fmaxf(m0, __shfl_xor(m0, 32, 64));
            if (quad == 0)
                out1[((size_t)b * H2 + nt * 16 + col) * PP + qq] = m0;
        }
    }
}

extern "C" void kernel_launch(void* const* d_in, const int* in_sizes, int n_in,
                              void* d_out, int out_size, void* d_ws, size_t ws_size,
                              hipStream_t stream) {
    const float* xyz  = (const float*)d_in[0];
    const float* feat = (const float*)d_in[1];
    const float* W1   = (const float*)d_in[2];
    const float* b1   = (const float*)d_in[3];
    const float* g1   = (const float*)d_in[4];
    const float* be1  = (const float*)d_in[5];
    const float* m1   = (const float*)d_in[6];
    const float* v1   = (const float*)d_in[7];
    const float* W2   = (const float*)d_in[8];
    const float* b2   = (const float*)d_in[9];
    const float* g2   = (const float*)d_in[10];
    const float* be2  = (const float*)d_in[11];
    const float* m2   = (const float*)d_in[12];
    const float* v2   = (const float*)d_in[13];

    char* ws = (char*)d_ws;
    float*          fxt  = (float*)(ws + OFF_FXT);
    float4*         pts4 = (float4*)(ws + OFF_PTS4);
    int*            knn  = (int*)(ws + OFF_KNN);
    unsigned short* w1p  = (unsigned short*)(ws + OFF_W1P);
    unsigned short* w2p  = (unsigned short*)(ws + OFF_W2P);
    float*          c1   = (float*)(ws + OFF_C1);
    float*          c2   = (float*)(ws + OFF_C2);

    float* out0 = (float*)d_out;                       // new_xyz  (B,P,3)
    float* out1 = out0 + (size_t)BB * PP * 3;          // new_feat (B,128,P)
    float* out2 = out1 + (size_t)BB * H2 * PP;         // sample_idx (B,P) as float

    hipLaunchKernelGGL(k0_weights, dim3(77), dim3(256), 0, stream,
                       W1, b1, g1, be1, m1, v1, W2, b2, g2, be2, m2, v2,
                       w1p, w2p, c1, c2);
    hipLaunchKernelGGL(k1_prep, dim3(1024), dim3(512), 0, stream,
                       xyz, feat, fxt, pts4, out0, out2);
    hipLaunchKernelGGL(k2_knn, dim3(256), dim3(256), 0, stream, pts4, knn);
    hipLaunchKernelGGL(k3_mlp, dim3(512), dim3(256), 0, stream,
                       fxt, knn, w1p, w2p, c1, c2, out1);
}

// Round 2
// 191.857 us; speedup vs baseline: 1.5152x; 1.5152x over previous
//
#include <hip/hip_runtime.h>
#include <hip/hip_bf16.h>

// Problem constants
#define BB 8
#define NN 8192
#define CC 64
#define PP 2048
#define KK 16
#define H1 64
#define H2 128
#define K1PAD 160
#define K2PAD 72

typedef float  f32x4 __attribute__((ext_vector_type(4)));
typedef short  s16x8 __attribute__((ext_vector_type(8)));

// ---- workspace layout (bytes) ----
#define OFF_FXT   0u                    // B*N*68 f32 = 17,825,792
#define OFF_PTS4  17825792u             // B*N float4 = 2,097,152
#define OFF_KNN   19922944u             // B*P*16 int  = 1,048,576
#define OFF_W1P   20971520u             // 64*160 bf16 = 20,480
#define OFF_W2P   20992000u             // 128*72 bf16 = 18,432
#define OFF_C1    21010432u             // 64 f32
#define OFF_C2    21010688u             // 128 f32

static __device__ __forceinline__ unsigned short bf16b(float v) {
    __hip_bfloat16 h = __float2bfloat16(v);
    return *reinterpret_cast<unsigned short*>(&h);
}
static __device__ __forceinline__ unsigned pk2(float a, float b) {
    return ((unsigned)bf16b(b) << 16) | (unsigned)bf16b(a);
}

// ---------------- K0: fold BN into weights, write bf16 W1p/W2p + c1/c2 ----
__global__ void k0_weights(const float* __restrict__ W1, const float* __restrict__ b1,
                           const float* __restrict__ g1, const float* __restrict__ be1,
                           const float* __restrict__ m1, const float* __restrict__ v1,
                           const float* __restrict__ W2, const float* __restrict__ b2,
                           const float* __restrict__ g2, const float* __restrict__ be2,
                           const float* __restrict__ m2, const float* __restrict__ v2,
                           unsigned short* __restrict__ w1p, unsigned short* __restrict__ w2p,
                           float* __restrict__ c1, float* __restrict__ c2) {
    int i = blockIdx.x * 256 + threadIdx.x;
    if (i < 64 * K1PAD) {
        int n = i / K1PAD, c = i - n * K1PAD;
        float s = g1[n] * rsqrtf(v1[n] + 1e-5f);
        float val = 0.f;
        if (c < 67)                 val = W1[n * 134 + c] * s;
        else if (c >= 72 && c < 139) val = W1[n * 134 + (c - 5)] * s;
        w1p[i] = bf16b(val);
    }
    int j = i - 64 * K1PAD;
    if (j >= 0 && j < 128 * K2PAD) {
        int o = j / K2PAD, k = j - o * K2PAD;
        float s = g2[o] * rsqrtf(v2[o] + 1e-5f);
        w2p[j] = bf16b((k < 64) ? W2[o * 64 + k] * s : 0.f);
    }
    int l = i - (64 * K1PAD + 128 * K2PAD);
    if (l >= 0 && l < 64) {
        float s = g1[l] * rsqrtf(v1[l] + 1e-5f);
        c1[l] = s * (b1[l] - m1[l]) + be1[l];
    }
    int p = l - 64;
    if (p >= 0 && p < 128) {
        float s = g2[p] * rsqrtf(v2[p] + 1e-5f);
        c2[p] = s * (b2[p] - m2[p]) + be2[p];
    }
}

// ---------------- K1: transpose feat -> fxt[b][n][68], pts4, out0, out2 ----
__global__ __launch_bounds__(512) void k1_prep(const float* __restrict__ xyz,
                                               const float* __restrict__ feat,
                                               float* __restrict__ fxt,
                                               float4* __restrict__ pts4,
                                               float* __restrict__ out0,
                                               float* __restrict__ out2) {
    __shared__ float tile[68][65];
    int b  = blockIdx.x >> 7;
    int n0 = (blockIdx.x & 127) * 64;
    int tx = threadIdx.x & 63, ty = threadIdx.x >> 6;
    for (int c = ty; c < 68; c += 8) {
        float v;
        if (c < 64)       v = feat[((size_t)b * 64 + c) * NN + n0 + tx];
        else if (c < 67)  v = xyz[((size_t)b * NN + n0 + tx) * 3 + (c - 64)];
        else              v = 0.f;
        tile[c][tx] = v;
    }
    __syncthreads();
    size_t base = ((size_t)b * NN + n0) * 68;
    for (int e = threadIdx.x; e < 64 * 68; e += 512) {
        int nl = e / 68, c = e - nl * 68;
        fxt[base + e] = tile[c][nl];
    }
    if (threadIdx.x < 64) {
        int n = n0 + threadIdx.x;
        float x = tile[64][threadIdx.x], y = tile[65][threadIdx.x], z = tile[66][threadIdx.x];
        pts4[(size_t)b * NN + n] = make_float4(x, y, z, x * x + y * y + z * z);
        if (n0 < PP) out2[b * PP + n] = (float)n;
    }
    if (n0 < PP) {
        for (int e = threadIdx.x; e < 64 * 3; e += 512) {
            int nl = e / 3, d = e - nl * 3;
            out0[((size_t)b * PP + n0 + nl) * 3 + d] = tile[64 + d][nl];
        }
    }
}

// ---------------- K2 v2: exact KNN, LDS-staged, swizzled, register top-k ----
// Block 256 thr (4 waves); wave handles 8 queries. Grid 512: b=blk>>6,
// 32 queries/block. Candidate i=r*64+c stored at LDS slot r*64+((c+r)&63):
//   staging writes: rotated-contiguous (conflict-free), global coalesced
//   phase1: lane reads own row in rotated order (balanced banks)
//   phase2: 64 lanes read row sl contiguously (conflict-free)
__global__ __launch_bounds__(256) void k2_knn(const float4* __restrict__ pts4,
                                              int* __restrict__ knn) {
    __shared__ float4 stage[4096];   // 64 KB
    int lane = threadIdx.x & 63;
    int wv   = threadIdx.x >> 6;
    int b    = blockIdx.x >> 6;
    int q0   = (blockIdx.x & 63) * 32 + wv * 8;
    size_t pb = (size_t)b * NN;

    float4 qc = make_float4(0.f, 0.f, 0.f, 0.f);
    if (lane < 8) qc = pts4[pb + q0 + lane];
    float qx2 = -2.f * qc.x, qy2 = -2.f * qc.y, qz2 = -2.f * qc.z;
    float bx[8], by[8], bz[8];
#pragma unroll
    for (int q = 0; q < 8; ++q) {
        bx[q] = __shfl(qx2, q); by[q] = __shfl(qy2, q); bz[q] = __shfl(qz2, q);
    }

    float mA[8], mB[8];
#pragma unroll
    for (int q = 0; q < 8; ++q) { mA[q] = 3.402823466e+38f; mB[q] = 3.402823466e+38f; }

    // stage half h into LDS (swizzled)
    auto stage_half = [&](int h) {
        const float4* src = pts4 + pb + h * 4096;
        for (int i = threadIdx.x; i < 4096; i += 256) {
            float4 v = src[i];
            int r = i >> 6, c = i & 63;
            stage[(r << 6) | ((c + r) & 63)] = v;
        }
    };
    // per-lane min over own row (64 candidates), for all 8 queries
    auto phase1 = [&](float* m) {
#pragma unroll
        for (int t8 = 0; t8 < 8; ++t8) {
            float4 cc[8];
#pragma unroll
            for (int i = 0; i < 8; ++i)
                cc[i] = stage[(lane << 6) | ((t8 * 8 + i + lane) & 63)];
#pragma unroll
            for (int q = 0; q < 8; ++q) {
                float x = bx[q], y = by[q], z = bz[q];
#pragma unroll
                for (int i = 0; i < 8; i += 2) {
                    float e0 = fmaf(z, cc[i].z, fmaf(y, cc[i].y, fmaf(x, cc[i].x, cc[i].w)));
                    float e1 = fmaf(z, cc[i+1].z, fmaf(y, cc[i+1].y, fmaf(x, cc[i+1].x, cc[i+1].w)));
                    m[q] = fminf(fminf(m[q], e0), e1);
                }
            }
        }
    };

    stage_half(0);
    __syncthreads();
    phase1(mA);
    __syncthreads();
    stage_half(1);
    __syncthreads();
    phase1(mB);

    // threshold T[q] = 16th smallest of the 64 lane-mins (bitonic sort)
    float T[8];
#pragma unroll
    for (int q = 0; q < 8; ++q) {
        float v = fminf(mA[q], mB[q]);
#pragma unroll
        for (int k = 2; k <= 64; k <<= 1) {
#pragma unroll
            for (int j = k >> 1; j > 0; j >>= 1) {
                float p = __shfl_xor(v, j, 64);
                bool up = ((lane & k) == 0);
                bool lo = ((lane & j) == 0);
                float mn = fminf(v, p), mx = fmaxf(v, p);
                v = (up == lo) ? mn : mx;
            }
        }
        T[q] = __shfl(v, 15, 64);
    }

    float keep_d[8]; int keep_n[8]; int cnt[8];
#pragma unroll
    for (int q = 0; q < 8; ++q) { keep_d[q] = 3.402823466e+38f; keep_n[q] = 0x7FFFFFFF; cnt[q] = 0; }

    // rescan selected rows of half h (currently staged), compact into lane regs
    auto scan_half = [&](int h, float* mH) {
#pragma unroll
        for (int q = 0; q < 8; ++q) {
            unsigned long long rm = __ballot(mH[q] <= T[q]);
            float x = bx[q], y = by[q], z = bz[q], tq = T[q];
            while (rm) {
                int sl = __ffsll((long long)rm) - 1; rm &= rm - 1;
                float4 c = stage[(sl << 6) | lane];
                float e = fmaf(z, c.z, fmaf(y, c.y, fmaf(x, c.x, c.w)));
                int n = (h << 12) | (sl << 6) | ((lane - sl) & 63);
                unsigned long long bal = __ballot(e <= tq);
                while (bal) {
                    int src = __ffsll((long long)bal) - 1; bal &= bal - 1;
                    float ed = __shfl(e, src);
                    int   nd = __shfl(n, src);
                    if (lane == cnt[q]) { keep_d[q] = ed; keep_n[q] = nd; }
                    cnt[q]++;
                }
            }
        }
    };

    scan_half(1, mB);        // half B is in LDS now
    __syncthreads();
    stage_half(0);           // restore half A
    __syncthreads();
    scan_half(0, mA);

    // rank selection among kept candidates (M <= 64, one per lane)
#pragma unroll
    for (int q = 0; q < 8; ++q) {
        int M = min(cnt[q], 64);
        float di = keep_d[q]; int ni = keep_n[q];
        int rank = 0;
        for (int j = 0; j < M; ++j) {
            float dj = __shfl(keep_d[q], j);
            int   nj = __shfl(keep_n[q], j);
            rank += (dj < di || (dj == di && nj < ni)) ? 1 : 0;
        }
        if (lane < M && rank < 16)
            knn[((size_t)(b * PP + q0 + q)) * KK + rank] = ni;
    }
}

// ---------------- K3: gather + MFMA MLP + maxpool (one wave per block) ----
__global__ __launch_bounds__(64, 2) void k3_mlp(const float* __restrict__ fxt,
                                                const int* __restrict__ knn,
                                                const unsigned short* __restrict__ w1p,
                                                const unsigned short* __restrict__ w2p,
                                                const float* __restrict__ c1,
                                                const float* __restrict__ c2,
                                                float* __restrict__ out1) {
    // LDS: [0,5120) E(16x160 bf16), [5120,7424) h1(16x72 bf16),
    // [7424,7696) t4 (17 float4), [7696,7832) tbd (34 u32)
    __shared__ __align__(16) char seg[8192];
    int lane = threadIdx.x;
    int wg   = blockIdx.x;                      // 2048 waves
    float4* sh_t4 = (float4*)(seg + 7424);
    unsigned* sh_tbd = (unsigned*)(seg + 7696);
    unsigned short* h1l = (unsigned short*)(seg + 5120);

    int col = lane & 15, quad = lane >> 4;

    s16x8 w1f[5][4];
#pragma unroll
    for (int ks = 0; ks < 5; ++ks)
#pragma unroll
        for (int nt = 0; nt < 4; ++nt)
            w1f[ks][nt] = *(const s16x8*)(w1p + (nt * 16 + col) * K1PAD + ks * 32 + quad * 8);
    s16x8 w2f[2][8];
#pragma unroll
    for (int ks = 0; ks < 2; ++ks)
#pragma unroll
        for (int nt = 0; nt < 8; ++nt)
            w2f[ks][nt] = *(const s16x8*)(w2p + (nt * 16 + col) * K2PAD + ks * 32 + quad * 8);
    float c1v[4], c2v[8];
#pragma unroll
    for (int nt = 0; nt < 4; ++nt) c1v[nt] = c1[nt * 16 + col];
#pragma unroll
    for (int nt = 0; nt < 8; ++nt) c2v[nt] = c2[nt * 16 + col];

    for (int it = 0; it < 8; ++it) {
        int qlin = wg + 2048 * it;
        int b = qlin >> 11, qq = qlin & 2047;
        const float4* fx4 = (const float4*)fxt;
        __syncthreads();
        if (lane < 17) {
            float4 v = fx4[((size_t)b * NN + qq) * 17 + lane];
            sh_t4[lane] = v;
            sh_tbd[lane * 2]     = pk2(v.x, v.y);
            sh_tbd[lane * 2 + 1] = pk2(v.z, v.w);
        }
        __syncthreads();
        {
            int r = lane >> 2, s = lane & 3;
            int nidx = knn[((size_t)b * PP + qq) * KK + r];
            const float4* rowp = fx4 + ((size_t)b * NN + nidx) * 17;
            char* erow = seg + r * 320;
#pragma unroll
            for (int j = 0; j < 5; ++j) {
                int c4 = j * 4 + s;
                if (c4 < 17) {
                    float4 v = rowp[c4], t = sh_t4[c4];
                    *(unsigned*)(erow + c4 * 8)     = pk2(v.x - t.x, v.y - t.y);
                    *(unsigned*)(erow + c4 * 8 + 4) = pk2(v.z - t.z, v.w - t.w);
                }
            }
            for (int j = s; j < 34; j += 4)
                *(unsigned*)(erow + 144 + j * 4) = sh_tbd[j];
#pragma unroll
            for (int j = s; j < 12; j += 4) {
                int w = (j < 2) ? (34 + j) : (68 + j);
                *(unsigned*)(erow + w * 4) = 0u;
            }
        }
        __syncthreads();
        f32x4 acc1[4];
#pragma unroll
        for (int nt = 0; nt < 4; ++nt) acc1[nt] = (f32x4){0.f, 0.f, 0.f, 0.f};
#pragma unroll
        for (int ks = 0; ks < 5; ++ks) {
            s16x8 a = *(const s16x8*)(seg + (lane & 15) * 320 + ks * 64 + quad * 16);
#pragma unroll
            for (int nt = 0; nt < 4; ++nt)
                acc1[nt] = __builtin_amdgcn_mfma_f32_16x16x32_bf16(a, w1f[ks][nt], acc1[nt], 0, 0, 0);
        }
#pragma unroll
        for (int nt = 0; nt < 4; ++nt) {
#pragma unroll
            for (int r = 0; r < 4; ++r) {
                float y = fmaxf(acc1[nt][r] + c1v[nt], 0.f);
                h1l[(quad * 4 + r) * K2PAD + nt * 16 + col] = bf16b(y);
            }
        }
        __syncthreads();
        f32x4 acc2[8];
#pragma unroll
        for (int nt = 0; nt < 8; ++nt) acc2[nt] = (f32x4){0.f, 0.f, 0.f, 0.f};
#pragma unroll
        for (int ks = 0; ks < 2; ++ks) {
            s16x8 a = *(const s16x8*)(seg + 5120 + (lane & 15) * 144 + ks * 64 + quad * 16);
#pragma unroll
            for (int nt = 0; nt < 8; ++nt)
                acc2[nt] = __builtin_amdgcn_mfma_f32_16x16x32_bf16(a, w2f[ks][nt], acc2[nt], 0, 0, 0);
        }
#pragma unroll
        for (int nt = 0; nt < 8; ++nt) {
            float m0 = fmaxf(fmaxf(acc2[nt][0], acc2[nt][1]), fmaxf(acc2[nt][2], acc2[nt][3]));
            m0 = m0 + c2v[nt];
            m0 = fmaxf(m0, 0.f);
            m0 = fmaxf(m0, __shfl_xor(m0, 16, 64));
            m0 = fmaxf(m0, __shfl_xor(m0, 32, 64));
            if (quad == 0)
                out1[((size_t)b * H2 + nt * 16 + col) * PP + qq] = m0;
        }
    }
}

extern "C" void kernel_launch(void* const* d_in, const int* in_sizes, int n_in,
                              void* d_out, int out_size, void* d_ws, size_t ws_size,
                              hipStream_t stream) {
    const float* xyz  = (const float*)d_in[0];
    const float* feat = (const float*)d_in[1];
    const float* W1   = (const float*)d_in[2];
    const float* b1   = (const float*)d_in[3];
    const float* g1   = (const float*)d_in[4];
    const float* be1  = (const float*)d_in[5];
    const float* m1   = (const float*)d_in[6];
    const float* v1   = (const float*)d_in[7];
    const float* W2   = (const float*)d_in[8];
    const float* b2   = (const float*)d_in[9];
    const float* g2   = (const float*)d_in[10];
    const float* be2  = (const float*)d_in[11];
    const float* m2   = (const float*)d_in[12];
    const float* v2   = (const float*)d_in[13];

    char* ws = (char*)d_ws;
    float*          fxt  = (float*)(ws + OFF_FXT);
    float4*         pts4 = (float4*)(ws + OFF_PTS4);
    int*            knn  = (int*)(ws + OFF_KNN);
    unsigned short* w1p  = (unsigned short*)(ws + OFF_W1P);
    unsigned short* w2p  = (unsigned short*)(ws + OFF_W2P);
    float*          c1   = (float*)(ws + OFF_C1);
    float*          c2   = (float*)(ws + OFF_C2);

    float* out0 = (float*)d_out;
    float* out1 = out0 + (size_t)BB * PP * 3;
    float* out2 = out1 + (size_t)BB * H2 * PP;

    hipLaunchKernelGGL(k0_weights, dim3(77), dim3(256), 0, stream,
                       W1, b1, g1, be1, m1, v1, W2, b2, g2, be2, m2, v2,
                       w1p, w2p, c1, c2);
    hipLaunchKernelGGL(k1_prep, dim3(1024), dim3(512), 0, stream,
                       xyz, feat, fxt, pts4, out0, out2);
    hipLaunchKernelGGL(k2_knn, dim3(512), dim3(256), 0, stream, pts4, knn);
    hipLaunchKernelGGL(k3_mlp, dim3(2048), dim3(64), 0, stream,
                       fxt, knn, w1p, w2p, c1, c2, out1);
}

// Round 3
// 176.053 us; speedup vs baseline: 1.6512x; 1.0898x over previous
//
#include <hip/hip_runtime.h>
#include <hip/hip_bf16.h>

// Problem constants
#define BB 8
#define NN 8192
#define CC 64
#define PP 2048
#define KK 16
#define H1 64
#define H2 128
#define K1PAD 160
#define K2PAD 72

typedef float  f32x4 __attribute__((ext_vector_type(4)));
typedef short  s16x8 __attribute__((ext_vector_type(8)));

// ---- workspace layout (bytes) ----
#define OFF_FXT   0u                    // B*N*68 f32 = 17,825,792
#define OFF_PTS4  17825792u             // B*N float4 = 2,097,152
#define OFF_KNN   19922944u             // B*P*16 int  = 1,048,576
#define OFF_W1P   20971520u             // 64*160 bf16 = 20,480
#define OFF_W2P   20992000u             // 128*72 bf16 = 18,432
#define OFF_C1    21010432u             // 64 f32
#define OFF_C2    21010688u             // 128 f32

static __device__ __forceinline__ unsigned short bf16b(float v) {
    __hip_bfloat16 h = __float2bfloat16(v);
    return *reinterpret_cast<unsigned short*>(&h);
}
static __device__ __forceinline__ unsigned pk2(float a, float b) {
    return ((unsigned)bf16b(b) << 16) | (unsigned)bf16b(a);
}

// ---------------- K0: fold BN into weights, write bf16 W1p/W2p + c1/c2 ----
__global__ void k0_weights(const float* __restrict__ W1, const float* __restrict__ b1,
                           const float* __restrict__ g1, const float* __restrict__ be1,
                           const float* __restrict__ m1, const float* __restrict__ v1,
                           const float* __restrict__ W2, const float* __restrict__ b2,
                           const float* __restrict__ g2, const float* __restrict__ be2,
                           const float* __restrict__ m2, const float* __restrict__ v2,
                           unsigned short* __restrict__ w1p, unsigned short* __restrict__ w2p,
                           float* __restrict__ c1, float* __restrict__ c2) {
    int i = blockIdx.x * 256 + threadIdx.x;
    if (i < 64 * K1PAD) {
        int n = i / K1PAD, c = i - n * K1PAD;
        float s = g1[n] * rsqrtf(v1[n] + 1e-5f);
        float val = 0.f;
        if (c < 67)                 val = W1[n * 134 + c] * s;
        else if (c >= 72 && c < 139) val = W1[n * 134 + (c - 5)] * s;
        w1p[i] = bf16b(val);
    }
    int j = i - 64 * K1PAD;
    if (j >= 0 && j < 128 * K2PAD) {
        int o = j / K2PAD, k = j - o * K2PAD;
        float s = g2[o] * rsqrtf(v2[o] + 1e-5f);
        w2p[j] = bf16b((k < 64) ? W2[o * 64 + k] * s : 0.f);
    }
    int l = i - (64 * K1PAD + 128 * K2PAD);
    if (l >= 0 && l < 64) {
        float s = g1[l] * rsqrtf(v1[l] + 1e-5f);
        c1[l] = s * (b1[l] - m1[l]) + be1[l];
    }
    int p = l - 64;
    if (p >= 0 && p < 128) {
        float s = g2[p] * rsqrtf(v2[p] + 1e-5f);
        c2[p] = s * (b2[p] - m2[p]) + be2[p];
    }
}

// ---------------- K1: transpose feat -> fxt[b][n][68], pts4, out0, out2 ----
__global__ __launch_bounds__(512) void k1_prep(const float* __restrict__ xyz,
                                               const float* __restrict__ feat,
                                               float* __restrict__ fxt,
                                               float4* __restrict__ pts4,
                                               float* __restrict__ out0,
                                               float* __restrict__ out2) {
    __shared__ float tile[68][65];
    int b  = blockIdx.x >> 7;
    int n0 = (blockIdx.x & 127) * 64;
    int tx = threadIdx.x & 63, ty = threadIdx.x >> 6;
    for (int c = ty; c < 68; c += 8) {
        float v;
        if (c < 64)       v = feat[((size_t)b * 64 + c) * NN + n0 + tx];
        else if (c < 67)  v = xyz[((size_t)b * NN + n0 + tx) * 3 + (c - 64)];
        else              v = 0.f;
        tile[c][tx] = v;
    }
    __syncthreads();
    size_t base = ((size_t)b * NN + n0) * 68;
    for (int e = threadIdx.x; e < 64 * 68; e += 512) {
        int nl = e / 68, c = e - nl * 68;
        fxt[base + e] = tile[c][nl];
    }
    if (threadIdx.x < 64) {
        int n = n0 + threadIdx.x;
        float x = tile[64][threadIdx.x], y = tile[65][threadIdx.x], z = tile[66][threadIdx.x];
        pts4[(size_t)b * NN + n] = make_float4(x, y, z, x * x + y * y + z * z);
        if (n0 < PP) out2[b * PP + n] = (float)n;
    }
    if (n0 < PP) {
        for (int e = threadIdx.x; e < 64 * 3; e += 512) {
            int nl = e / 3, d = e - nl * 3;
            out0[((size_t)b * PP + n0 + nl) * 3 + d] = tile[64 + d][nl];
        }
    }
}

// ---------------- K2 v3: exact KNN, whole batch staged once (128 KB LDS) ----
// 256 blocks x 1024 thr (16 waves, 1 block/CU, ~50% occ). Block stages its
// batch's 8192 pts once; ONE barrier; waves then independent, 4 queries each.
// Swizzle slot(r,c) = r*64 + ((c + (r>>1)) & 63):
//   staging: wave writes one row, rotated contiguous (balanced)
//   phase1:  lane L reads rows 2L/2L+1, logical col j -> phys (j+L)&63 (balanced)
//   phase2:  64 lanes read row 2*sl+rr at phys (lane+sl)&63 (conflict-free)
// Selection: T = 16th-smallest lane-min (bitonic); survivor compaction via
// ballot prefix-sum scatter into per-wave LDS scratch (no serial shuffles);
// final 64-lane bitonic (d,idx) pair sort; lanes 0..15 write ranks.
__global__ __launch_bounds__(1024, 4) void k2_knn(const float4* __restrict__ pts4,
                                                  int* __restrict__ knn) {
    __shared__ float4 stage[8192];        // 128 KB
    __shared__ float2 scratch[16][64];    // 8 KB per-wave survivor buffers
    int lane = threadIdx.x & 63;
    int wv   = threadIdx.x >> 6;
    int b    = blockIdx.x >> 5;                 // 32 blocks per batch
    int q0   = (blockIdx.x & 31) * 64 + wv * 4; // 4 queries per wave
    size_t pb = (size_t)b * NN;

    // query coefficients
    float4 qc = make_float4(0.f, 0.f, 0.f, 0.f);
    if (lane < 4) qc = pts4[pb + q0 + lane];
    float qx2 = -2.f * qc.x, qy2 = -2.f * qc.y, qz2 = -2.f * qc.z;
    float bx[4], by[4], bz[4];
#pragma unroll
    for (int q = 0; q < 4; ++q) {
        bx[q] = __shfl(qx2, q); by[q] = __shfl(qy2, q); bz[q] = __shfl(qz2, q);
    }

    // stage all 8192 points (coalesced reads; swizzled, balanced LDS writes)
#pragma unroll
    for (int i = 0; i < 8; ++i) {
        int p = i * 1024 + threadIdx.x;
        float4 v = pts4[pb + p];
        int r = p >> 6, c = p & 63;
        stage[(r << 6) | ((c + (r >> 1)) & 63)] = v;
    }
    __syncthreads();   // the only block barrier

    // Phase 1: per-lane min over its 128 candidates (rows 2L, 2L+1)
    float m[4];
#pragma unroll
    for (int q = 0; q < 4; ++q) m[q] = 3.402823466e+38f;
#pragma unroll
    for (int rr = 0; rr < 2; ++rr) {
        int rowbase = (2 * lane + rr) << 6;
#pragma unroll
        for (int j8 = 0; j8 < 8; ++j8) {
            float4 cc[8];
#pragma unroll
            for (int i = 0; i < 8; ++i)
                cc[i] = stage[rowbase | ((j8 * 8 + i + lane) & 63)];
#pragma unroll
            for (int q = 0; q < 4; ++q) {
                float x = bx[q], y = by[q], z = bz[q];
#pragma unroll
                for (int i = 0; i < 8; i += 2) {
                    float e0 = fmaf(z, cc[i].z, fmaf(y, cc[i].y, fmaf(x, cc[i].x, cc[i].w)));
                    float e1 = fmaf(z, cc[i+1].z, fmaf(y, cc[i+1].y, fmaf(x, cc[i+1].x, cc[i+1].w)));
                    m[q] = fminf(fminf(m[q], e0), e1);
                }
            }
        }
    }

    // per-query: threshold, rescan+compact, exact sort, write
#pragma unroll 1
    for (int q = 0; q < 4; ++q) {
        // T = 16th smallest of 64 lane-mins (value-only bitonic sort)
        float v = m[q];
#pragma unroll
        for (int k = 2; k <= 64; k <<= 1) {
#pragma unroll
            for (int j = k >> 1; j > 0; j >>= 1) {
                float p = __shfl_xor(v, j, 64);
                bool up = ((lane & k) == 0);
                bool lo = ((lane & j) == 0);
                float mn = fminf(v, p), mx = fmaxf(v, p);
                v = (up == lo) ? mn : mx;
            }
        }
        float tq = __shfl(v, 15, 64);

        // Phase 2: rescan selected lanes' rows, scatter survivors to scratch
        float x = bx[q], y = by[q], z = bz[q];
        unsigned long long rm = __ballot(m[q] <= tq);
        int cnt = 0;
        unsigned long long below = (lane == 63) ? 0x7FFFFFFFFFFFFFFFull
                                                : ((1ull << lane) - 1ull);
        while (rm) {
            int sl = __ffsll((long long)rm) - 1; rm &= rm - 1;
            int phys = (lane + sl) & 63;
            float4 c0 = stage[((2 * sl) << 6) | phys];
            float4 c1 = stage[((2 * sl + 1) << 6) | phys];
            float e0 = fmaf(z, c0.z, fmaf(y, c0.y, fmaf(x, c0.x, c0.w)));
            float e1 = fmaf(z, c1.z, fmaf(y, c1.y, fmaf(x, c1.x, c1.w)));
            unsigned long long b0 = __ballot(e0 <= tq);
            if (e0 <= tq) {
                int pos = cnt + __popcll(b0 & below);
                if (pos < 64)
                    scratch[wv][pos] = make_float2(e0, __int_as_float(sl * 128 + lane));
            }
            cnt += __popcll(b0);
            unsigned long long b1 = __ballot(e1 <= tq);
            if (e1 <= tq) {
                int pos = cnt + __popcll(b1 & below);
                if (pos < 64)
                    scratch[wv][pos] = make_float2(e1, __int_as_float(sl * 128 + 64 + lane));
            }
            cnt += __popcll(b1);
        }
        __threadfence_block();   // drain LDS writes before readback (wave-local)
        int M = min(cnt, 64);
        float2 kv = scratch[wv][lane];
        float kd = (lane < M) ? kv.x : 3.402823466e+38f;
        int   kn = (lane < M) ? __float_as_int(kv.y) : 0x7FFFFFFF;

        // exact 64-lane bitonic pair sort ascending by (d, idx)
#pragma unroll
        for (int k = 2; k <= 64; k <<= 1) {
#pragma unroll
            for (int j = k >> 1; j > 0; j >>= 1) {
                float pd = __shfl_xor(kd, j, 64);
                int   pn = __shfl_xor(kn, j, 64);
                bool takeMin = (((lane & k) == 0) == ((lane & j) == 0));
                bool pLess = (pd < kd) || (pd == kd && pn < kn);
                bool sw = takeMin ? pLess : !pLess;
                kd = sw ? pd : kd;
                kn = sw ? pn : kn;
            }
        }
        if (lane < 16)
            knn[((size_t)(b * PP + q0 + q)) * KK + lane] = kn;
        __threadfence_block();   // order scratch reuse across queries
    }
}

// ---------------- K3: gather + MFMA MLP + maxpool (one wave per block) ----
__global__ __launch_bounds__(64, 2) void k3_mlp(const float* __restrict__ fxt,
                                                const int* __restrict__ knn,
                                                const unsigned short* __restrict__ w1p,
                                                const unsigned short* __restrict__ w2p,
                                                const float* __restrict__ c1,
                                                const float* __restrict__ c2,
                                                float* __restrict__ out1) {
    // LDS: [0,5120) E(16x160 bf16), [5120,7424) h1(16x72 bf16),
    // [7424,7696) t4 (17 float4), [7696,7832) tbd (34 u32)
    __shared__ __align__(16) char seg[8192];
    int lane = threadIdx.x;
    int wg   = blockIdx.x;                      // 2048 waves
    float4* sh_t4 = (float4*)(seg + 7424);
    unsigned* sh_tbd = (unsigned*)(seg + 7696);
    unsigned short* h1l = (unsigned short*)(seg + 5120);

    int col = lane & 15, quad = lane >> 4;

    s16x8 w1f[5][4];
#pragma unroll
    for (int ks = 0; ks < 5; ++ks)
#pragma unroll
        for (int nt = 0; nt < 4; ++nt)
            w1f[ks][nt] = *(const s16x8*)(w1p + (nt * 16 + col) * K1PAD + ks * 32 + quad * 8);
    s16x8 w2f[2][8];
#pragma unroll
    for (int ks = 0; ks < 2; ++ks)
#pragma unroll
        for (int nt = 0; nt < 8; ++nt)
            w2f[ks][nt] = *(const s16x8*)(w2p + (nt * 16 + col) * K2PAD + ks * 32 + quad * 8);
    float c1v[4], c2v[8];
#pragma unroll
    for (int nt = 0; nt < 4; ++nt) c1v[nt] = c1[nt * 16 + col];
#pragma unroll
    for (int nt = 0; nt < 8; ++nt) c2v[nt] = c2[nt * 16 + col];

    for (int it = 0; it < 8; ++it) {
        int qlin = wg + 2048 * it;
        int b = qlin >> 11, qq = qlin & 2047;
        const float4* fx4 = (const float4*)fxt;
        __syncthreads();
        if (lane < 17) {
            float4 v = fx4[((size_t)b * NN + qq) * 17 + lane];
            sh_t4[lane] = v;
            sh_tbd[lane * 2]     = pk2(v.x, v.y);
            sh_tbd[lane * 2 + 1] = pk2(v.z, v.w);
        }
        __syncthreads();
        {
            int r = lane >> 2, s = lane & 3;
            int nidx = knn[((size_t)b * PP + qq) * KK + r];
            const float4* rowp = fx4 + ((size_t)b * NN + nidx) * 17;
            char* erow = seg + r * 320;
#pragma unroll
            for (int j = 0; j < 5; ++j) {
                int c4 = j * 4 + s;
                if (c4 < 17) {
                    float4 v = rowp[c4], t = sh_t4[c4];
                    *(unsigned*)(erow + c4 * 8)     = pk2(v.x - t.x, v.y - t.y);
                    *(unsigned*)(erow + c4 * 8 + 4) = pk2(v.z - t.z, v.w - t.w);
                }
            }
            for (int j = s; j < 34; j += 4)
                *(unsigned*)(erow + 144 + j * 4) = sh_tbd[j];
#pragma unroll
            for (int j = s; j < 12; j += 4) {
                int w = (j < 2) ? (34 + j) : (68 + j);
                *(unsigned*)(erow + w * 4) = 0u;
            }
        }
        __syncthreads();
        f32x4 acc1[4];
#pragma unroll
        for (int nt = 0; nt < 4; ++nt) acc1[nt] = (f32x4){0.f, 0.f, 0.f, 0.f};
#pragma unroll
        for (int ks = 0; ks < 5; ++ks) {
            s16x8 a = *(const s16x8*)(seg + (lane & 15) * 320 + ks * 64 + quad * 16);
#pragma unroll
            for (int nt = 0; nt < 4; ++nt)
                acc1[nt] = __builtin_amdgcn_mfma_f32_16x16x32_bf16(a, w1f[ks][nt], acc1[nt], 0, 0, 0);
        }
#pragma unroll
        for (int nt = 0; nt < 4; ++nt) {
#pragma unroll
            for (int r = 0; r < 4; ++r) {
                float y = fmaxf(acc1[nt][r] + c1v[nt], 0.f);
                h1l[(quad * 4 + r) * K2PAD + nt * 16 + col] = bf16b(y);
            }
        }
        __syncthreads();
        f32x4 acc2[8];
#pragma unroll
        for (int nt = 0; nt < 8; ++nt) acc2[nt] = (f32x4){0.f, 0.f, 0.f, 0.f};
#pragma unroll
        for (int ks = 0; ks < 2; ++ks) {
            s16x8 a = *(const s16x8*)(seg + 5120 + (lane & 15) * 144 + ks * 64 + quad * 16);
#pragma unroll
            for (int nt = 0; nt < 8; ++nt)
                acc2[nt] = __builtin_amdgcn_mfma_f32_16x16x32_bf16(a, w2f[ks][nt], acc2[nt], 0, 0, 0);
        }
#pragma unroll
        for (int nt = 0; nt < 8; ++nt) {
            float m0 = fmaxf(fmaxf(acc2[nt][0], acc2[nt][1]), fmaxf(acc2[nt][2], acc2[nt][3]));
            m0 = m0 + c2v[nt];
            m0 = fmaxf(m0, 0.f);
            m0 = fmaxf(m0, __shfl_xor(m0, 16, 64));
            m0 = fmaxf(m0, __shfl_xor(m0, 32, 64));
            if (quad == 0)
                out1[((size_t)b * H2 + nt * 16 + col) * PP + qq] = m0;
        }
    }
}

extern "C" void kernel_launch(void* const* d_in, const int* in_sizes, int n_in,
                              void* d_out, int out_size, void* d_ws, size_t ws_size,
                              hipStream_t stream) {
    const float* xyz  = (const float*)d_in[0];
    const float* feat = (const float*)d_in[1];
    const float* W1   = (const float*)d_in[2];
    const float* b1   = (const float*)d_in[3];
    const float* g1   = (const float*)d_in[4];
    const float* be1  = (const float*)d_in[5];
    const float* m1   = (const float*)d_in[6];
    const float* v1   = (const float*)d_in[7];
    const float* W2   = (const float*)d_in[8];
    const float* b2   = (const float*)d_in[9];
    const float* g2   = (const float*)d_in[10];
    const float* be2  = (const float*)d_in[11];
    const float* m2   = (const float*)d_in[12];
    const float* v2   = (const float*)d_in[13];

    char* ws = (char*)d_ws;
    float*          fxt  = (float*)(ws + OFF_FXT);
    float4*         pts4 = (float4*)(ws + OFF_PTS4);
    int*            knn  = (int*)(ws + OFF_KNN);
    unsigned short* w1p  = (unsigned short*)(ws + OFF_W1P);
    unsigned short* w2p  = (unsigned short*)(ws + OFF_W2P);
    float*          c1   = (float*)(ws + OFF_C1);
    float*          c2   = (float*)(ws + OFF_C2);

    float* out0 = (float*)d_out;
    float* out1 = out0 + (size_t)BB * PP * 3;
    float* out2 = out1 + (size_t)BB * H2 * PP;

    hipLaunchKernelGGL(k0_weights, dim3(77), dim3(256), 0, stream,
                       W1, b1, g1, be1, m1, v1, W2, b2, g2, be2, m2, v2,
                       w1p, w2p, c1, c2);
    hipLaunchKernelGGL(k1_prep, dim3(1024), dim3(512), 0, stream,
                       xyz, feat, fxt, pts4, out0, out2);
    hipLaunchKernelGGL(k2_knn, dim3(256), dim3(1024), 0, stream, pts4, knn);
    hipLaunchKernelGGL(k3_mlp, dim3(2048), dim3(64), 0, stream,
                       fxt, knn, w1p, w2p, c1, c2, out1);
}